// Round 7
// baseline (256.162 us; speedup 1.0000x reference)
//
#include <hip/hip_runtime.h>

namespace {
constexpr int CC    = 10;                  // cluster gap window C
constexpr int TT    = 500;                 // time steps
constexpr int NN    = 128;                 // neurons per batch row
constexpr int G     = 10;                  // t-segments per trace
constexpr int LSEG  = TT / G;              // 50 core steps
constexpr int HALO  = CC;                  // 10
constexpr int ROWS  = LSEG + 2 * HALO;     // 70 rows scanned per segment
constexpr int NSLOT = 10;                  // ws record: 5 cluster maxes + 5 scalars
constexpr int MAXG  = TT / (CC + 1) + 1;   // 46 max global clusters
}

// ---------------- kernel A: bulk-register load, then pure-VALU branchless scan ----------------
// Structure: issue ALL 70 independent column loads (17.9 KB/wave in flight), ONE
// vmcnt wait, then a fully-unrolled branchless scan with compile-time register
// indexing. No per-row memory latency on the critical path.
__global__ __launch_bounds__(128, 4)
void seg_scan_kernel(const float* __restrict__ vmem, float* __restrict__ ws) {
    const int s   = blockIdx.x;            // segment 0..9
    const int b   = blockIdx.y;
    const int tid = threadIdx.x;           // neuron 0..127
    const int a   = s * LSEG;
    const float* __restrict__ col = vmem + (size_t)b * TT * NN + tid;

    __shared__ float stg[5 * NN];          // 2.5 KB: open-cluster max scratch

    // ---- bulk load: 70 independent dword loads, addresses clamped ----
    float v[ROWS];
    #pragma unroll
    for (int r = 0; r < ROWS; ++r) {
        int t = a - HALO + r;
        t = t < 0 ? 0 : (t > TT - 1 ? TT - 1 : t);
        v[r] = col[(size_t)t * NN];
    }
    // mask out-of-range rows (wave-uniform scalar branches)
    if (s == 0) {
        #pragma unroll
        for (int r = 0; r < HALO; ++r) v[r] = -1.0f;
    }
    if (s == G - 1) {
        #pragma unroll
        for (int r = LSEG + HALO; r < ROWS; ++r) v[r] = -1.0f;
    }

    // ---- branchless scan (exact round-4..6 semantics) ----
    int   ls = -(1 << 20), lcount = 0, hdne = 0, tmn = 0, hasu = 0;
    float ccm = -1e30f, rmax = -1e30f, hdm = -1e30f, vmx = -1e30f, m0 = -1e30f;

    #pragma unroll
    for (int r = 0; r < ROWS; ++r) {
        const int ofs = r - HALO;          // compile-time
        const int t   = a + ofs;
        const float x = v[r];
        const bool spike = x >= 0.0f;
        if (ofs >= 0 && ofs < LSEG) {      // core accounting (compile-time guard)
            const float rm2     = fmaxf(rmax, x);
            const bool  recent  = (t - ls <= CC);      // spike within C
            const bool  isStart = spike && !recent;
            const bool  contS   = spike && recent;
            const bool  hd      = contS && (lcount == 0);   // head-continuation
            hdm  = hd ? fmaxf(hdm, rm2) : hdm;
            hdne = hd ? 1 : hdne;
            const float folded = fmaxf(ccm, rm2);
            ccm  = isStart ? x : ((contS && lcount > 0) ? folded : ccm);
            lcount += isStart ? 1 : 0;
            rmax = spike ? -1e30f : rm2;
            if (x > vmx) { vmx = x; tmn = t; }         // strict >: first argmax
            const int idx = lcount > 0 ? lcount - 1 : 0;
            stg[idx * NN + tid] = ccm;     // unconditional; final write per slot wins
        }
        if (spike) ls = t;                 // halo spikes count for ls (cndmask)
        if (r >= 2 * HALO) {               // eval u = t-10, u in [a, a+50)
            const float vu = v[r - HALO];  // register, compile-time index
            const bool  um = ls < t - 2 * CC;
            hasu = um ? 1 : hasu;
            m0   = um ? fmaxf(m0, vu) : m0;
        }
    }

    // ---- coalesced output: 10 rows of 512 B ----
    float* __restrict__ wsl = ws + (size_t)(b * G + s) * NSLOT * NN + tid;
    #pragma unroll
    for (int i = 0; i < 5; ++i)
        wsl[i * NN] = (i < lcount) ? stg[i * NN + tid] : 0.0f;
    const int packed = lcount | (hdne << 3) | (hasu << 4) | (tmn << 5);
    wsl[5 * NN] = __int_as_float(packed);
    wsl[6 * NN] = hdm;     // head-piece max
    wsl[7 * NN] = rmax;    // tail gap max (since last core spike)
    wsl[8 * NN] = vmx;
    wsl[9 * NN] = m0;
}

// ---------------- kernel B: merge segments + loss (1 wave per 64 neurons) ----------------
__global__ __launch_bounds__(64)
void merge_kernel(const float* __restrict__ vmem, const float* __restrict__ ws,
                  const int* __restrict__ labels, float* __restrict__ out) {
    const int bb = blockIdx.x, lane = threadIdx.x;
    const int b = bb >> 1, n = ((bb & 1) << 6) | lane;
    __shared__ float gl[MAXG * 64];        // 11.8 KB compact global cluster list
    __shared__ float wb[512];              // pass-2 column staging

    // streaming double-buffered ws reads: 10 values per segment in flight
    const float* __restrict__ wsb = ws + (size_t)b * G * NSLOT * NN + n;
    float f[2][10];
    auto loadSeg = [&](int slot, int s2) {
        const float* p = wsb + (size_t)s2 * NSLOT * NN;
        #pragma unroll
        for (int i = 0; i < 10; ++i) f[slot][i] = p[i * NN];
    };
    loadSeg(0, 0);

    int g = 0, g_nc = 0, g_hasu = 0, g_tm = 0;
    bool open = false; float cur = -1e30f, ptg = -1e30f;
    float g_vmax = -1e30f, g_m0 = -1e30f;
    #pragma unroll
    for (int s2 = 0; s2 < G; ++s2) {
        if (s2 + 1 < G) loadSeg((s2 + 1) & 1, s2 + 1);
        const float (&d)[10] = f[s2 & 1];
        const int pk = __float_as_int(d[5]);
        const int k = pk & 7, hne = (pk >> 3) & 1;
        g_nc += k; g_hasu |= (pk >> 4) & 1;
        if (d[8] > g_vmax) { g_vmax = d[8]; g_tm = pk >> 5; }
        if (d[9] > g_m0) g_m0 = d[9];
        if (open) {
            if (hne) { cur = fmaxf(cur, fmaxf(ptg, d[6])); ptg = d[7]; }
            if (k > 0 || !hne) { gl[g * 64 + lane] = cur; ++g; open = false; }
        }
        if (k > 0) {
            #pragma unroll
            for (int i = 0; i < 4; ++i)
                if (i < k - 1) { gl[g * 64 + lane] = d[i]; ++g; }
            float last = d[4];                 // select d[k-1]
            if (k == 1) last = d[0];
            else if (k == 2) last = d[1];
            else if (k == 3) last = d[2];
            else if (k == 4) last = d[3];
            cur = last; open = true; ptg = d[7];
        }
    }
    if (open) { gl[g * 64 + lane] = cur; ++g; }        // g == g_nc

    const int label = labels[b * NN + n];

    // pass-2 m_rest: wave-cooperative, rare
    const bool need2 = (label > g_nc) && g_hasu && (label - g_nc >= 2);
    float mrest = g_vmax;                              // full2 surrogate default
    unsigned long long bal = __ballot(need2);
    const float* colbase = vmem + (size_t)b * TT * NN;
    while (bal) {
        const int fl = __ffsll((unsigned long long)bal) - 1;
        bal &= bal - 1;
        const int   nf    = ((bb & 1) << 6) | fl;      // flagged neuron
        const int   tmf   = __shfl(g_tm, fl);
        const float vmaxf = __shfl(g_vmax, fl);
        #pragma unroll
        for (int j = 0; j < 8; ++j) {                  // stage column: 8 loads/lane
            const int t = lane * 8 + j;
            wb[t] = (t < TT) ? colbase[(size_t)t * NN + nf] : -1.0f;
        }
        __syncthreads();                               // single wave: cheap
        int ls2 = -1000, lh = 0; float lm = -1e30f;
        const int u0 = lane * 8;
        for (int t2 = u0 - 10; t2 < u0 + 18; ++t2) {
            const float v = (t2 >= 0 && t2 < 512) ? wb[t2] : -1.0f;
            if (v >= 0.0f) ls2 = t2;
            const int u = t2 - 10;
            if (u >= u0 && u < u0 + 8 && u < TT) {
                if (ls2 < u - 10 && (u < tmf - CC / 2 || u > tmf + CC / 2)) {
                    lh = 1; const float vu = wb[u]; if (vu > lm) lm = vu;
                }
            }
        }
        #pragma unroll
        for (int off = 32; off > 0; off >>= 1) {       // wave reduce
            lm = fmaxf(lm, __shfl_down(lm, off));
            lh |= __shfl_down(lh, off);
        }
        const float res = __shfl(lh ? lm : vmaxf, 0);
        if (lane == fl) mrest = res;
        __syncthreads();
    }

    // branch select
    float contrib = 0.0f;
    if (label > g_nc) {
        if (!g_hasu) contrib = g_vmax;                 // full0 -> vmax
        else {
            const float dE = (float)(label - g_nc);    // >= 1
            contrib = -((g_m0 + (dE - 1.0f) * mrest) / dE);
        }
    } else if (label < g_nc) {
        const int kk = g_nc - label;                   // 1..nc
        float ssum = 0.0f;
        for (int i = 0; i < kk; ++i) {                 // sum kk smallest cluster maxes
            float mn = 1e30f; int mj = 0;
            for (int jj = 0; jj < g_nc; ++jj) {
                const float x = gl[jj * 64 + lane];
                if (x < mn) { mn = x; mj = jj; }
            }
            ssum += mn; gl[mj * 64 + lane] = 1e30f;
        }
        contrib = ssum / (float)kk;
    }

    out[1 + b * NN + n] = (float)g_nc;                 // spike_output

    float w = contrib;
    #pragma unroll
    for (int off = 32; off > 0; off >>= 1) w += __shfl_down(w, off);
    if (lane == 0) atomicAdd(out, w);
}

extern "C" void kernel_launch(void* const* d_in, const int* in_sizes, int n_in,
                              void* d_out, int out_size, void* d_ws, size_t ws_size,
                              hipStream_t stream) {
    const float* vmem   = (const float*)d_in[0];
    // d_in[1] (vlastmem) and d_in[3] (ratio) are unused by the reference forward.
    const int*   labels = (const int*)d_in[2];
    float*       out    = (float*)d_out;
    float*       ws     = (float*)d_ws;   // 256*10*10*128*4 = 13.1 MB

    const int B = in_sizes[2] / NN;       // 256

    hipMemsetAsync(out, 0, sizeof(float), stream);     // zero the loss accumulator
    hipLaunchKernelGGL(seg_scan_kernel, dim3(G, B), dim3(NN), 0, stream, vmem, ws);
    hipLaunchKernelGGL(merge_kernel, dim3(2 * B), dim3(64), 0, stream, vmem, ws, labels, out);
}